// Round 1
// baseline (526.698 us; speedup 1.0000x reference)
//
#include <hip/hip_runtime.h>
#include <hip/hip_bf16.h>

// DynaConv: out[b,o,l] = sum_j kern[b,l,o,j]*u[b,l,j] + bias[o]
//   kern[b,l,o,j] = sum_h W2[o*288+j,h]*h[b,l,h] + b2[o*288+j]
//   h[b,l,:] = tanh(W1 @ u[b,l,:] + b1)
// Restructured: out = sum_h h[p,h]*s[p,o,h] + t[p,o] + bias[o]
//   s[p,o,h] = sum_j W2[(o*288+j)*32+h]*u[p,j]   (the big contraction)
//   t[p,o]   = sum_j b2[o*288+j]*u[p,j]

#define TP 16           // pixels per block
#define CKK 288
#define NB 512          // (2*4096)/TP blocks

__global__ __launch_bounds__(256) void dynaconv_kernel(
    const float* __restrict__ x,    // [2,32,64,64]
    const float* __restrict__ W1,   // [32,288]
    const float* __restrict__ b1,   // [32]
    const float* __restrict__ W2,   // [9216,32]
    const float* __restrict__ b2,   // [9216]
    const float* __restrict__ bias, // [32]
    float* __restrict__ out)        // [2,32,4096]
{
    __shared__ float u_lds[CKK * TP];      // [j][p]
    __shared__ float t_lds[32 * TP];       // [o][p]
    __shared__ float red_lds[4 * 32 * TP]; // [wave][o][p]

    const int t    = threadIdx.x;
    const int p    = t & 15;
    const int grp  = t >> 4;   // 0..15, owns h/o pair {grp*2, grp*2+1}
    const int wave = t >> 6;   // 0..3
    const int lane = t & 63;
    const int h0   = grp * 2;

    const int g0  = blockIdx.x * TP;   // first global pixel
    const int b   = g0 >> 12;          // / 4096
    const int l0  = g0 & 4095;
    const int y   = l0 >> 6;
    const int wx0 = l0 & 63;

    // ---- Phase A: fused unfold -> u tile in LDS (u[j][p]) ----
    {
        const int jb = grp;  // 0..15
        for (int k = 0; k < 18; ++k) {
            int j = k * 16 + jb;            // covers 0..287
            int c = j / 9, r = j % 9;
            int ki = r / 3, kj = r % 3;
            int y2 = y + ki - 1;
            int x2 = wx0 + p + kj - 1;
            float v = 0.f;
            if ((unsigned)y2 < 64u && (unsigned)x2 < 64u)
                v = x[((b * 32 + c) * 64 + y2) * 64 + x2];
            u_lds[j * TP + p] = v;
        }
    }
    __syncthreads();

    // ---- Phase B: h (2 per thread, kept in regs) and t[o][p] ----
    float h_reg[2];
    {
        float ah0 = 0.f, ah1 = 0.f, at0 = 0.f, at1 = 0.f;
        const float* w1a = W1 + (h0    ) * CKK;
        const float* w1b = W1 + (h0 + 1) * CKK;
        const float* b2a = b2 + (h0    ) * CKK;
        const float* b2b = b2 + (h0 + 1) * CKK;
        for (int j = 0; j < CKK; ++j) {
            float uv = u_lds[j * TP + p];
            ah0 += uv * w1a[j];
            ah1 += uv * w1b[j];
            at0 += uv * b2a[j];
            at1 += uv * b2b[j];
        }
        h_reg[0] = tanhf(ah0 + b1[h0]);
        h_reg[1] = tanhf(ah1 + b1[h0 + 1]);
        t_lds[(h0    ) * TP + p] = at0;
        t_lds[(h0 + 1) * TP + p] = at1;
        // t_lds consumed only after the barrier following Phase C
    }

    // ---- Phase C: s contraction, acc[8 o][2 h] in regs ----
    for (int oc = 0; oc < 4; ++oc) {
        float acc[8][2];
        #pragma unroll
        for (int oo = 0; oo < 8; ++oo) { acc[oo][0] = 0.f; acc[oo][1] = 0.f; }

        for (int jc = 0; jc < 18; ++jc) {
            float ur[16];
            #pragma unroll
            for (int k = 0; k < 16; ++k)
                ur[k] = u_lds[(jc * 16 + k) * TP + p];

            #pragma unroll
            for (int oo = 0; oo < 8; ++oo) {
                const int o = oc * 8 + oo;
                const float2* w2p =
                    (const float2*)(W2 + ((size_t)(o * CKK + jc * 16)) * 32 + h0);
                #pragma unroll
                for (int k = 0; k < 16; ++k) {
                    float2 v = w2p[k * 16];  // stride 32 floats between j's
                    acc[oo][0] += ur[k] * v.x;
                    acc[oo][1] += ur[k] * v.y;
                }
            }
        }

        #pragma unroll
        for (int oo = 0; oo < 8; ++oo) {
            const int o = oc * 8 + oo;
            float partial = h_reg[0] * acc[oo][0] + h_reg[1] * acc[oo][1];
            partial += __shfl_xor(partial, 16, 64);  // fold grps within wave
            partial += __shfl_xor(partial, 32, 64);
            if (lane < 16)
                red_lds[(wave * 32 + o) * TP + p] = partial;
        }
    }
    __syncthreads();

    // ---- Output: sum 4 wave-partials + t + bias ----
    {
        const int p2 = t & 15;
        #pragma unroll
        for (int pass = 0; pass < 2; ++pass) {
            const int o = (t >> 4) + pass * 16;
            float s = t_lds[o * TP + p2] + bias[o];
            #pragma unroll
            for (int w = 0; w < 4; ++w)
                s += red_lds[(w * 32 + o) * TP + p2];
            out[((size_t)(b * 32 + o)) * 4096 + l0 + p2] = s;
        }
    }
}

extern "C" void kernel_launch(void* const* d_in, const int* in_sizes, int n_in,
                              void* d_out, int out_size, void* d_ws, size_t ws_size,
                              hipStream_t stream) {
    const float* x    = (const float*)d_in[0];
    const float* W1   = (const float*)d_in[1];
    const float* b1   = (const float*)d_in[2];
    const float* W2   = (const float*)d_in[3];
    const float* b2   = (const float*)d_in[4];
    const float* bias = (const float*)d_in[5];
    float* out = (float*)d_out;

    dynaconv_kernel<<<NB, 256, 0, stream>>>(x, W1, b1, W2, b2, bias, out);
}

// Round 2
// 32.505 us; speedup vs baseline: 16.2034x; 16.2034x over previous
//
#include <hip/hip_runtime.h>
#include <hip/hip_bf16.h>

// DynaConv restructured as MFMA GEMMs.
//   u[p,j]  : fused unfold of x (bf16, LDS per 32-pixel tile)
//   S[p,(o,h)] = sum_j u[p,j] * W2b[(o*32+h), j]      (main GEMM, K=288)
//   hh[p,h] = tanh(sum_j u[p,j]*W1[h,j] + b1[h])      (small GEMM)
//   t[p,o]  = sum_j u[p,j]*b2[o*288+j]                (small GEMM)
//   out[p,o] = sum_h hh[p,h]*S[p,o,h] + t[p,o] + bias[o]
// W2b/W1b/b2b are bf16 weight copies built by prep_kernel into d_ws.

#define CKK 288
#define SJ  296   // padded j-stride for u_lds (bf16 elems): 592B rows, breaks pow2 banks

typedef __attribute__((ext_vector_type(8))) short short8;
typedef __attribute__((ext_vector_type(4))) float f32x4;

// ws layout in bf16 elements
#define W2B_OFF 0               // [1024][288]
#define W1B_OFF 294912          // [32][288]
#define B2B_OFF (294912 + 9216) // [32][288]
#define WS_ELEMS (294912 + 9216 + 9216)

__global__ __launch_bounds__(256) void prep_kernel(
    const float* __restrict__ W1, const float* __restrict__ W2,
    const float* __restrict__ b2, __hip_bfloat16* __restrict__ ws)
{
    int idx = blockIdx.x * 256 + threadIdx.x;
    if (idx < 294912) {
        // dest-ordered: n = idx/288 = o*32+h, j = idx%288 ; src W2[(o*288+j)*32+h]
        int n = idx / CKK, j = idx - n * CKK;
        int o = n >> 5, h = n & 31;
        ws[W2B_OFF + idx] = __float2bfloat16(W2[(o * CKK + j) * 32 + h]);
    } else if (idx < 294912 + 9216) {
        int k = idx - 294912;
        ws[W1B_OFF + k] = __float2bfloat16(W1[k]);
    } else if (idx < WS_ELEMS) {
        int k = idx - (294912 + 9216);
        ws[B2B_OFF + k] = __float2bfloat16(b2[k]);
    }
}

__global__ __launch_bounds__(512) void dynaconv_main(
    const float* __restrict__ x,     // [2,32,64,64]
    const float* __restrict__ b1,    // [32]
    const float* __restrict__ bias,  // [32]
    const __hip_bfloat16* __restrict__ ws,
    float* __restrict__ out)         // [2,32,4096]
{
    __shared__ __hip_bfloat16 u_lds[32 * SJ];  // [p][j]
    __shared__ float hh_lds[32 * 33];          // [p][h]
    __shared__ float o_lds[32 * 33];           // [p][o], seeded with t+bias

    const int t  = threadIdx.x;
    const int w  = t >> 6;   // wave 0..7
    const int l  = t & 63;
    const int lg = l >> 4;   // k-group 0..3
    const int lr = l & 15;

    const int g0  = blockIdx.x * 32;  // first global pixel
    const int b   = g0 >> 12;
    const int l0  = g0 & 4095;
    const int y   = l0 >> 6;
    const int wx0 = l0 & 63;

    // ---- Phase A: fused unfold -> u_lds (bf16) ----
    #pragma unroll
    for (int k = 0; k < 18; ++k) {
        int idx = k * 512 + t;        // 9216 = 32p * 288j
        int j = idx >> 5, p = idx & 31;
        int c = j / 9, r = j - c * 9;
        int ki = r / 3, kj = r - ki * 3;
        int y2 = y + ki - 1;
        int x2 = wx0 + p + kj - 1;
        float v = 0.f;
        if ((unsigned)y2 < 64u && (unsigned)x2 < 64u)
            v = x[((b * 32 + c) * 64 + y2) * 64 + x2];
        u_lds[p * SJ + j] = __float2bfloat16(v);
    }
    __syncthreads();

    // ---- Phase B: waves 0-1: t+bias -> o_lds ; waves 2-3: hh -> hh_lds ----
    if (w < 4) {
        const __hip_bfloat16* Bmat = ws + ((w < 2) ? B2B_OFF : W1B_OFF);
        const int col = ((w & 1) * 16) + lr;   // o or h column
        f32x4 acc0 = {0.f, 0.f, 0.f, 0.f}, acc1 = {0.f, 0.f, 0.f, 0.f};
        #pragma unroll
        for (int kb = 0; kb < 9; ++kb) {
            short8 bf = *(const short8*)(Bmat + col * CKK + kb * 32 + lg * 8);
            short8 a0 = *(const short8*)(u_lds + lr * SJ + kb * 32 + lg * 8);
            short8 a1 = *(const short8*)(u_lds + (16 + lr) * SJ + kb * 32 + lg * 8);
            acc0 = __builtin_amdgcn_mfma_f32_16x16x32_bf16(a0, bf, acc0, 0, 0, 0);
            acc1 = __builtin_amdgcn_mfma_f32_16x16x32_bf16(a1, bf, acc1, 0, 0, 0);
        }
        if (w < 2) {
            float bv = bias[col];
            #pragma unroll
            for (int r = 0; r < 4; ++r) {
                o_lds[(lg * 4 + r) * 33 + col]        = acc0[r] + bv;
                o_lds[(16 + lg * 4 + r) * 33 + col]   = acc1[r] + bv;
            }
        } else {
            float b1v = b1[col];
            #pragma unroll
            for (int r = 0; r < 4; ++r) {
                hh_lds[(lg * 4 + r) * 33 + col]       = tanhf(acc0[r] + b1v);
                hh_lds[(16 + lg * 4 + r) * 33 + col]  = tanhf(acc1[r] + b1v);
            }
        }
    }
    __syncthreads();

    // ---- Phase C: main GEMM. wave w owns o = w*4..w*4+3 -> n = w*128..+127 ----
    f32x4 acc[2][8];
    #pragma unroll
    for (int m = 0; m < 2; ++m)
        #pragma unroll
        for (int nf = 0; nf < 8; ++nf)
            acc[m][nf] = f32x4{0.f, 0.f, 0.f, 0.f};

    {
        const __hip_bfloat16* W2b = ws + W2B_OFF;
        const int nbase = w * 128;
        // software pipeline: prefetch B for kb+1 while MFMAing kb
        short8 bcur[8];
        #pragma unroll
        for (int nf = 0; nf < 8; ++nf)
            bcur[nf] = *(const short8*)(W2b + (size_t)(nbase + nf * 16 + lr) * CKK + lg * 8);

        #pragma unroll
        for (int kb = 0; kb < 9; ++kb) {
            short8 a0 = *(const short8*)(u_lds + lr * SJ + kb * 32 + lg * 8);
            short8 a1 = *(const short8*)(u_lds + (16 + lr) * SJ + kb * 32 + lg * 8);
            short8 bnext[8];
            if (kb < 8) {
                #pragma unroll
                for (int nf = 0; nf < 8; ++nf)
                    bnext[nf] = *(const short8*)(W2b + (size_t)(nbase + nf * 16 + lr) * CKK
                                                 + (kb + 1) * 32 + lg * 8);
            }
            #pragma unroll
            for (int nf = 0; nf < 8; ++nf) {
                acc[0][nf] = __builtin_amdgcn_mfma_f32_16x16x32_bf16(a0, bcur[nf], acc[0][nf], 0, 0, 0);
                acc[1][nf] = __builtin_amdgcn_mfma_f32_16x16x32_bf16(a1, bcur[nf], acc[1][nf], 0, 0, 0);
            }
            if (kb < 8) {
                #pragma unroll
                for (int nf = 0; nf < 8; ++nf)
                    bcur[nf] = bnext[nf];
            }
        }
    }

    // ---- Epilogue: out[p,o] = sum_h hh[p,h]*S[p,o,h]  (+ t+bias already in o_lds) ----
    #pragma unroll
    for (int ol = 0; ol < 4; ++ol) {
        const int o = w * 4 + ol;
        #pragma unroll
        for (int m = 0; m < 2; ++m) {
            #pragma unroll
            for (int r = 0; r < 4; ++r) {
                const int p = m * 16 + lg * 4 + r;
                float v = hh_lds[p * 33 + lr]      * acc[m][ol * 2][r]
                        + hh_lds[p * 33 + 16 + lr] * acc[m][ol * 2 + 1][r];
                v += __shfl_xor(v, 1);
                v += __shfl_xor(v, 2);
                v += __shfl_xor(v, 4);
                v += __shfl_xor(v, 8);
                if (lr == 0) o_lds[p * 33 + o] += v;
            }
        }
    }
    __syncthreads();

    // ---- Store: coalesced over p ----
    #pragma unroll
    for (int k = 0; k < 2; ++k) {
        int idx = k * 512 + t;          // 1024 = 32o * 32p
        int o = idx >> 5, p = idx & 31;
        out[((size_t)(b * 32 + o)) * 4096 + l0 + p] = o_lds[p * 33 + o];
    }
}

extern "C" void kernel_launch(void* const* d_in, const int* in_sizes, int n_in,
                              void* d_out, int out_size, void* d_ws, size_t ws_size,
                              hipStream_t stream) {
    const float* x    = (const float*)d_in[0];
    const float* W1   = (const float*)d_in[1];
    const float* b1   = (const float*)d_in[2];
    const float* W2   = (const float*)d_in[3];
    const float* b2   = (const float*)d_in[4];
    const float* bias = (const float*)d_in[5];
    float* out = (float*)d_out;
    __hip_bfloat16* ws = (__hip_bfloat16*)d_ws;

    // weight reshape/convert: 313344 elements
    prep_kernel<<<(WS_ELEMS + 255) / 256, 256, 0, stream>>>(W1, W2, b2, ws);
    // main: 256 tiles of 32 pixels
    dynaconv_main<<<256, 512, 0, stream>>>(x, b1, bias, ws, out);
}